// Round 4
// baseline (365.879 us; speedup 1.0000x reference)
//
#include <hip/hip_runtime.h>

// Problem constants (fixed by reference setup_inputs)
#define BB 32
#define DD 64
#define HH 16
#define TT 256
#define KK 512
#define NN (BB*HH*TT)          // 131072 tokens
#define HT (HH*TT)             // 4096
#define DHT (DD*HT)            // 262144
#define ZQ_SIZE (BB*DD*HH*TT)
#define COMMIT_OFF ZQ_SIZE
#define IDX_OFF (ZQ_SIZE+1)
#define PPL_OFF (IDX_OFF+NN)
#define USE_OFF (PPL_OFF+1)

// ws layout (float offsets):
#define CNT_OFF    0       // counts[512]
#define CPART_OFF  512     // per-wave commit partials[2048] (plain stores)
#define CDELTA_OFF 2560    // rescue commitment correction (float atomic)
#define RC_OFF     2561    // int rescue count
#define DONE_OFF   2562    // int gate counter for fused stats
#define RLIST_OFF  2564    // (token:int, dminA:float-bits) pairs, up to RMAX
#define RMAX       24576
#define EBH_OFF    51720   // 512x64 f16 (RNE), code-major = 16384 floats

// token-adaptive rescue margin (dot scale): 2 dots x 2^-10*|z| + pack quantum
#define MARGIN_SCALE 1.953e-3f
#define MARGIN_CONST 1.2e-3f

using f16x8 = __attribute__((ext_vector_type(8))) _Float16;
using f32x4 = __attribute__((ext_vector_type(4))) float;

__device__ __forceinline__ f16x8 hc(uint4 v) { return __builtin_bit_cast(f16x8, v); }
__device__ __forceinline__ unsigned f16pair(float a, float b) {
    unsigned short ha = __builtin_bit_cast(unsigned short, (_Float16)a);  // RNE
    unsigned short hb = __builtin_bit_cast(unsigned short, (_Float16)b);
    return (unsigned)ha | ((unsigned)hb << 16);
}
__device__ __forceinline__ float pick4(float a0, float a1, float a2, float a3, int i) {
    float x = (i & 1) ? a1 : a0;
    float y = (i & 1) ? a3 : a2;
    return (i & 2) ? y : x;
}

// 32 blocks x 256: fp16(RNE) codebook, code-major linear; block 0 zeroes scalars.
__global__ void vq_init(const float* __restrict__ emb, float* __restrict__ ws) {
    const int tid = threadIdx.x, blk = blockIdx.x;
    if (blk == 0) {
        ws[CNT_OFF + tid] = 0.0f;
        ws[CNT_OFF + 256 + tid] = 0.0f;
        if (tid == 0) {
            ws[CDELTA_OFF] = 0.0f;
            ((int*)ws)[RC_OFF] = 0;
            ((int*)ws)[DONE_OFF] = 0;
        }
    }
    const int k  = blk * 16 + (tid >> 4);
    const int d0 = (tid & 15) * 4;
    float4 v = *reinterpret_cast<const float4*>(emb + k * DD + d0);
    uint2 w;
    w.x = f16pair(v.x, v.y);
    w.y = f16pair(v.z, v.w);
    reinterpret_cast<uint2*>(ws + EBH_OFF)[k * 16 + (d0 >> 2)] = w;
}

// Screen v5: fp16 single-MFMA screen (round-3 numerics) at 4 blocks/CU:
// 39 KB LDS + launch_bounds(256,4) -> 16 waves/CU, 2x round-0 occupancy at the
// SAME per-wave work (64 tokens/wave). Token-adaptive rescue margin.
__global__ __launch_bounds__(256, 4) void vq_screen(
    const float* __restrict__ z_e, const float* __restrict__ emb,
    float* __restrict__ ws, float* __restrict__ out_zq, float* __restrict__ out_idx)
{
    __shared__ uint4 sh[2304];      // 256 codes * 9 uint4 (padded) = 36,864 B
    __shared__ int hist[KK];        // + 2 KB

    const int tid  = threadIdx.x;
    const int lane = tid & 63;
    const int col  = lane & 15;
    const int q    = lane >> 4;
    const int W    = (blockIdx.x << 2) | (tid >> 6);   // global wave id, 0..2047
    const int base_tok = W * 64;

    hist[tid] = 0; hist[tid + 256] = 0;

    const uint4* eb4 = reinterpret_cast<const uint4*>(ws + EBH_OFF);

    // ---- A fragments: 4 token-tiles x 2 k-frags, fp16 RNE; + per-(s) |z|^2 partials
    f16x8 af[4][2];
    float zp[4];
#pragma unroll
    for (int s = 0; s < 4; ++s) {
        zp[s] = 0.0f;
        const int n = base_tok + s * 16 + col;
        const size_t zoff = (size_t)(n >> 12) * DHT + (size_t)((n >> 8) & 15) * 256 + (size_t)(n & 255);
#pragma unroll
        for (int kf = 0; kf < 2; ++kf) {
            const int d0 = kf * 32 + q * 8;
            unsigned hu[4];
#pragma unroll
            for (int jj = 0; jj < 4; ++jj) {
                float z0 = z_e[zoff + (size_t)(d0 + 2*jj + 0) * HT];
                float z1 = z_e[zoff + (size_t)(d0 + 2*jj + 1) * HT];
                zp[s] = fmaf(z0, z0, zp[s]);
                zp[s] = fmaf(z1, z1, zp[s]);
                hu[jj] = f16pair(z0, z1);
            }
            af[s][kf] = hc(make_uint4(hu[0], hu[1], hu[2], hu[3]));
        }
    }
    // complete per-token |z|^2 (sum over the 4 q-lanes of each col)
#pragma unroll
    for (int s = 0; s < 4; ++s) {
        zp[s] += __shfl_xor(zp[s], 16, 64);
        zp[s] += __shfl_xor(zp[s], 32, 64);
    }

    // top-2 packed-max state (code id in low 9 mantissa bits)
    float m1[4][4], m2[4][4];
#pragma unroll
    for (int s = 0; s < 4; ++s)
#pragma unroll
        for (int r = 0; r < 4; ++r) { m1[s][r] = -3.4e38f; m2[s][r] = -3.4e38f; }

    unsigned ktag = (unsigned)col;
    const int idx0 = col * 9 + q;   // this lane's uint4 row base within a code-tile

#pragma unroll
    for (int p = 0; p < 2; ++p) {
        if (p) __syncthreads();   // phase-0 reads done before overwrite
#pragma unroll
        for (int j = 0; j < 8; ++j) {
            const int local = j * 256 + tid;
            const int c = local >> 3, jj = local & 7;
            sh[c * 9 + jj] = eb4[p * 2048 + local];
        }
        __syncthreads();

        // prologue loads for ctl=0
        uint4 nh0 = sh[idx0], nh1 = sh[idx0 + 4];

#pragma unroll 4
        for (int ctl = 0; ctl < 16; ++ctl) {
            f16x8 b0 = hc(nh0), b1 = hc(nh1);
            if (ctl < 15) {   // prefetch next ctl BEFORE this ctl's MFMAs
                const int ni = idx0 + (ctl + 1) * 144;
                nh0 = sh[ni]; nh1 = sh[ni + 4];
            }
#pragma unroll
            for (int s = 0; s < 4; ++s) {
                f32x4 acc = {0.f, 0.f, 0.f, 0.f};
                acc = __builtin_amdgcn_mfma_f32_16x16x32_f16(af[s][0], b0, acc, 0, 0, 0);
                acc = __builtin_amdgcn_mfma_f32_16x16x32_f16(af[s][1], b1, acc, 0, 0, 0);
#pragma unroll
                for (int r = 0; r < 4; ++r) {
                    float pk = __uint_as_float((__float_as_uint(acc[r]) & 0xFFFFFE00u) | ktag);
                    m2[s][r] = __builtin_amdgcn_fmed3f(pk, m1[s][r], m2[s][r]);
                    m1[s][r] = fmaxf(m1[s][r], pk);
                }
            }
            ktag += 16u;
        }
    }

    // cross-lane top-2 merge: after this, ALL 16 col-lanes share identical m1/m2
#pragma unroll
    for (int msk = 1; msk <= 8; msk <<= 1) {
#pragma unroll
        for (int s = 0; s < 4; ++s)
#pragma unroll
            for (int r = 0; r < 4; ++r) {
                float o1 = __shfl_xor(m1[s][r], msk, 64);
                float o2 = __shfl_xor(m2[s][r], msk, 64);
                m2[s][r] = __builtin_amdgcn_fmed3f(m1[s][r], o1, fmaxf(m2[s][r], o2));
                m1[s][r] = fmaxf(m1[s][r], o1);
            }
    }

    // ---- per-lane writeout: lane handles token (s0 = col>>2, r0 = col&3, own q) ----
    const int s0 = col >> 2, r0 = col & 3;
    const int token = base_tok + s0 * 16 + q * 4 + r0;

    float m1v, m2v;
    {
        float a = pick4(m1[0][0], m1[0][1], m1[0][2], m1[0][3], r0);
        float b = pick4(m1[1][0], m1[1][1], m1[1][2], m1[1][3], r0);
        float c = pick4(m1[2][0], m1[2][1], m1[2][2], m1[2][3], r0);
        float d = pick4(m1[3][0], m1[3][1], m1[3][2], m1[3][3], r0);
        m1v = pick4(a, b, c, d, s0);
        a = pick4(m2[0][0], m2[0][1], m2[0][2], m2[0][3], r0);
        b = pick4(m2[1][0], m2[1][1], m2[1][2], m2[1][3], r0);
        c = pick4(m2[2][0], m2[2][1], m2[2][2], m2[2][3], r0);
        d = pick4(m2[3][0], m2[3][1], m2[3][2], m2[3][3], r0);
        m2v = pick4(a, b, c, d, s0);
    }
    // zsq of my token lives (for index s) on lane col==q*4+r0 (any q there)
    const int c0 = q * 4 + r0;
    float z0s = __shfl(zp[0], c0, 64);
    float z1s = __shfl(zp[1], c0, 64);
    float z2s = __shfl(zp[2], c0, 64);
    float z3s = __shfl(zp[3], c0, 64);
    const float zsqv = pick4(z0s, z1s, z2s, z3s, s0);

    const int k_sel = (int)(__float_as_uint(m1v) & 511u);
    const float dminA = fmaf(-2.0f, m1v, zsqv + 1.0f);   // ||z||^2 + 1 - 2*dot

    out_idx[token] = (float)k_sel;
    const float margin = MARGIN_SCALE * sqrtf(zsqv) + MARGIN_CONST;
    if (m1v - m2v < margin) {
        int* rc = (int*)ws + RC_OFF;
        int pp = atomicAdd(rc, 1);
        if (pp < RMAX) {
            int* rl = (int*)ws + RLIST_OFF;
            rl[2 * pp] = token;
            rl[2 * pp + 1] = (int)__float_as_uint(dminA);
        }
    }
    atomicAdd(&hist[k_sel], 1);

    // commitment: wave-reduce dminA -> one partial per wave (plain store)
    float csum = dminA;
#pragma unroll
    for (int off = 32; off > 0; off >>= 1) csum += __shfl_down(csum, off, 64);
    if (lane == 0) ws[CPART_OFF + W] = csum;

    // z_q: gather winner row (fp32, L2-hot) and write strided
    {
        const int b = token >> 12, h = (token >> 8) & 15, t = token & 255;
        const size_t zb = (size_t)b * DHT + (size_t)h * TT + (size_t)t;
        const float4* er = reinterpret_cast<const float4*>(emb + (size_t)k_sel * DD);
#pragma unroll
        for (int i = 0; i < 16; ++i) {
            float4 v = er[i];
            out_zq[zb + (size_t)(4*i+0) * HT] = v.x;
            out_zq[zb + (size_t)(4*i+1) * HT] = v.y;
            out_zq[zb + (size_t)(4*i+2) * HT] = v.z;
            out_zq[zb + (size_t)(4*i+3) * HT] = v.w;
        }
    }

    // histogram -> global (one pass per block)
    __syncthreads();
    int c = hist[tid];       if (c) atomicAdd(ws + CNT_OFF + tid,       (float)c);
    c     = hist[tid + 256]; if (c) atomicAdd(ws + CNT_OFF + tid + 256, (float)c);
}

// Rescue v4: batched exact fp32 rescan. Codebook staged fp32 in LDS column-major
// (bank-optimal b128 reads; no VGPR-caching gamble). 256 threads x 2 codes each,
// 16 tokens/batch: 2048 independent FMA + 288 LDS b128 per thread per batch,
// 4 barriers per 16 tokens (was ~12 per token). Fused stats via last-block gate.
__global__ __launch_bounds__(256) void vq_rescue_stats(
    const float* __restrict__ z_e, const float* __restrict__ emb,
    float* __restrict__ ws, float* __restrict__ out, float* __restrict__ out_idx)
{
    __shared__ float4 ecb[8192];     // 131072 B, column-major: ecb[j*512 + k]
    __shared__ float4 lzb[256];      // [token i][chunk j] = lzb[i*16+j], 4 KB
    __shared__ int    tok[16];
    __shared__ float  dmina[16];
    __shared__ float  zsqs[16];
    __shared__ float  rdst[64];      // [wave][token]
    __shared__ int    ridx[64];
    __shared__ int    winK[16];
    __shared__ float  sdV[256];
    __shared__ int    siV[256];
    __shared__ float  scom[256];
    __shared__ int    amlast;

    float* out_zq = out;
    const int tid = threadIdx.x;
    const int wv  = tid >> 6;
    const int ln  = tid & 63;
    int cnt = ((const int*)ws)[RC_OFF];
    if (cnt > RMAX) cnt = RMAX;
    const int* rl = (const int*)ws + RLIST_OFF;

    // ---- stage fp32 codebook into LDS (column-major), coalesced global reads ----
    {
        const float4* eg = reinterpret_cast<const float4*>(emb);
        for (int t = tid; t < 8192; t += 256) {
            const int k = t >> 4, j = t & 15;
            ecb[j * 512 + k] = eg[t];
        }
    }
    __syncthreads();

    // per-thread code pair + |e|^2
    const int k0 = tid, k1 = tid + 256;
    float esq0 = 0.f, esq1 = 0.f;
#pragma unroll
    for (int j = 0; j < 16; ++j) {
        float4 ea = ecb[j * 512 + k0];
        float4 eb = ecb[j * 512 + k1];
        esq0 = fmaf(ea.x, ea.x, esq0); esq0 = fmaf(ea.y, ea.y, esq0);
        esq0 = fmaf(ea.z, ea.z, esq0); esq0 = fmaf(ea.w, ea.w, esq0);
        esq1 = fmaf(eb.x, eb.x, esq1); esq1 = fmaf(eb.y, eb.y, esq1);
        esq1 = fmaf(eb.z, eb.z, esq1); esq1 = fmaf(eb.w, eb.w, esq1);
    }

    for (int base = blockIdx.x * 16; base < cnt; base += gridDim.x * 16) {
        // ---- stage batch: 16 threads/token load 4 z floats each ----
        {
            const int i = tid >> 4, dgrp = tid & 15;
            const int idx = base + i;
            const int n = (idx < cnt) ? rl[2 * idx] : rl[2 * (cnt - 1)];
            const size_t zoff = (size_t)(n >> 12) * DHT + (size_t)((n >> 8) & 15) * 256 + (size_t)(n & 255);
            float4 zz;
            zz.x = z_e[zoff + (size_t)(dgrp * 4 + 0) * HT];
            zz.y = z_e[zoff + (size_t)(dgrp * 4 + 1) * HT];
            zz.z = z_e[zoff + (size_t)(dgrp * 4 + 2) * HT];
            zz.w = z_e[zoff + (size_t)(dgrp * 4 + 3) * HT];
            lzb[i * 16 + dgrp] = zz;
            float sp = fmaf(zz.x, zz.x, fmaf(zz.y, zz.y, fmaf(zz.z, zz.z, zz.w * zz.w)));
#pragma unroll
            for (int m = 1; m <= 8; m <<= 1) sp += __shfl_xor(sp, m, 64);
            if (dgrp == 0) {
                zsqs[i] = sp;
                tok[i] = (idx < cnt) ? n : -1;
                dmina[i] = __uint_as_float((unsigned)rl[2 * idx + 1]);
            }
        }
        __syncthreads();

        // ---- distances: each thread -> 2 codes x 16 tokens ----
        float d0[16], d1[16];
#pragma unroll
        for (int i = 0; i < 16; ++i) { d0[i] = 0.f; d1[i] = 0.f; }
#pragma unroll
        for (int j = 0; j < 16; ++j) {
            const float4 ea = ecb[j * 512 + k0];
            const float4 eb = ecb[j * 512 + k1];
#pragma unroll
            for (int i = 0; i < 16; ++i) {
                const float4 z = lzb[i * 16 + j];
                d0[i] = fmaf(ea.x, z.x, d0[i]); d0[i] = fmaf(ea.y, z.y, d0[i]);
                d0[i] = fmaf(ea.z, z.z, d0[i]); d0[i] = fmaf(ea.w, z.w, d0[i]);
                d1[i] = fmaf(eb.x, z.x, d1[i]); d1[i] = fmaf(eb.y, z.y, d1[i]);
                d1[i] = fmaf(eb.z, z.z, d1[i]); d1[i] = fmaf(eb.w, z.w, d1[i]);
            }
        }
        // per-wave winner per token (exact compare, lowest-index tie-break)
#pragma unroll
        for (int i = 0; i < 16; ++i) {
            float va = fmaf(-2.f, d0[i], esq0);
            float vb = fmaf(-2.f, d1[i], esq1);
            float v = va; int kk = k0;
            if (vb < va) { v = vb; kk = k1; }
#pragma unroll
            for (int off = 1; off < 64; off <<= 1) {
                float ov = __shfl_xor(v, off, 64);
                int   ok = __shfl_xor(kk, off, 64);
                if (ov < v || (ov == v && ok < kk)) { v = ov; kk = ok; }
            }
            if (ln == 0) { rdst[wv * 16 + i] = v; ridx[wv * 16 + i] = kk; }
        }
        __syncthreads();

        // ---- finalize winners (threads 0..15, one per token) ----
        if (tid < 16) {
            float cd = 0.f;
            int wk = -1;
            const int n = tok[tid];
            if (n >= 0) {
                float bd = rdst[tid]; int bk = ridx[tid];
#pragma unroll
                for (int w = 1; w < 4; ++w) {
                    float d2 = rdst[w * 16 + tid]; int j2 = ridx[w * 16 + tid];
                    if (d2 < bd || (d2 == bd && j2 < bk)) { bd = d2; bk = j2; }
                }
                const float d_new = zsqs[tid] + bd;
                const int k_old = (int)out_idx[n];
                cd = d_new - dmina[tid];
                if (bk != k_old) {
                    out_idx[n] = (float)bk;
                    atomicAdd(ws + CNT_OFF + k_old, -1.0f);
                    atomicAdd(ws + CNT_OFF + bk,    1.0f);
                    wk = bk;
                }
            }
            winK[tid] = wk;
#pragma unroll
            for (int m = 1; m <= 8; m <<= 1) cd += __shfl_xor(cd, m, 64);
            if (tid == 0 && cd != 0.f) atomicAdd(ws + CDELTA_OFF, cd);
        }
        __syncthreads();

        // ---- patch z_q for changed tokens ----
        {
            const int i = tid >> 4, dgrp = tid & 15;
            const int bk = winK[i];
            if (bk >= 0) {
                const int n = tok[i];
                const size_t zoff = (size_t)(n >> 12) * DHT + (size_t)((n >> 8) & 15) * 256 + (size_t)(n & 255);
                const float4 e4 = ecb[dgrp * 512 + bk];
                out_zq[zoff + (size_t)(dgrp * 4 + 0) * HT] = e4.x;
                out_zq[zoff + (size_t)(dgrp * 4 + 1) * HT] = e4.y;
                out_zq[zoff + (size_t)(dgrp * 4 + 2) * HT] = e4.z;
                out_zq[zoff + (size_t)(dgrp * 4 + 3) * HT] = e4.w;
            }
        }
        __syncthreads();
    }

    // ---- gate: last block to finish runs the stats reduction ----
    __threadfence();
    if (tid == 0) {
        int d = atomicAdd((int*)ws + DONE_OFF, 1);
        amlast = (d == (int)gridDim.x - 1) ? 1 : 0;
    }
    __syncthreads();
    if (!amlast) return;

    // stats: 256 threads x 2 codes each; counts/cdelta via agent-scope atomic loads
    {
        const int k = tid;
        const float c0 = __hip_atomic_load(ws + CNT_OFF + k,       __ATOMIC_RELAXED, __HIP_MEMORY_SCOPE_AGENT);
        const float c1 = __hip_atomic_load(ws + CNT_OFF + k + 256, __ATOMIC_RELAXED, __HIP_MEMORY_SCOPE_AGENT);
        const float p0 = c0 * (1.0f / (float)NN);
        const float p1 = c1 * (1.0f / (float)NN);
        sdV[k] = p0 * logf(p0 + 1e-12f) + p1 * logf(p1 + 1e-12f);
        siV[k] = ((p0 > 0.0f) ? 1 : 0) + ((p1 > 0.0f) ? 1 : 0);
        float cs = 0.0f;
#pragma unroll
        for (int i = 0; i < 8; ++i) cs += ws[CPART_OFF + k + 256 * i];
        scom[k] = cs;
        __syncthreads();
        for (int off = 128; off > 0; off >>= 1) {
            if (k < off) {
                sdV[k]  += sdV[k + off];
                siV[k]  += siV[k + off];
                scom[k] += scom[k + off];
            }
            __syncthreads();
        }
        if (k == 0) {
            float cdelta = __hip_atomic_load(ws + CDELTA_OFF, __ATOMIC_RELAXED, __HIP_MEMORY_SCOPE_AGENT);
            out[COMMIT_OFF] = 0.25f * (scom[0] + cdelta) / (float)ZQ_SIZE;
            out[PPL_OFF]    = expf(-sdV[0]);
            out[USE_OFF]    = (float)siV[0] / (float)KK;
        }
    }
}

extern "C" void kernel_launch(void* const* d_in, const int* in_sizes, int n_in,
                              void* d_out, int out_size, void* d_ws, size_t ws_size,
                              hipStream_t stream) {
    const float* z_e = (const float*)d_in[0];
    const float* emb = (const float*)d_in[1];
    float* out = (float*)d_out;
    float* ws  = (float*)d_ws;

    float* out_idx = out + IDX_OFF;

    vq_init<<<32, 256, 0, stream>>>(emb, ws);
    vq_screen<<<512, 256, 0, stream>>>(z_e, emb, ws, out, out_idx);
    vq_rescue_stats<<<256, 256, 0, stream>>>(z_e, emb, ws, out, out_idx);
}

// Round 5
// 214.750 us; speedup vs baseline: 1.7037x; 1.7037x over previous
//
#include <hip/hip_runtime.h>

// Problem constants (fixed by reference setup_inputs)
#define BB 32
#define DD 64
#define HH 16
#define TT 256
#define KK 512
#define NN (BB*HH*TT)          // 131072 tokens
#define HT (HH*TT)             // 4096
#define DHT (DD*HT)            // 262144
#define ZQ_SIZE (BB*DD*HH*TT)
#define COMMIT_OFF ZQ_SIZE
#define IDX_OFF (ZQ_SIZE+1)
#define PPL_OFF (IDX_OFF+NN)
#define USE_OFF (PPL_OFF+1)

// ws layout (float offsets):
#define CNT_OFF    0       // counts[512]
#define CPART_OFF  512     // per-wave commit partials[2048] (plain stores)
#define CDELTA_OFF 2560    // rescue commitment correction (float atomic)
#define RC_OFF     2561    // int rescue count
#define DONE_OFF   2562    // int gate counter for fused stats
#define RLIST_OFF  2564    // (token:int, dminA:float-bits) pairs, up to RMAX
#define RMAX       24576
#define EBH_OFF    51720   // 512x64 f16 (RNE), code-major = 16384 floats

// token-adaptive rescue margin (dot scale): 2 dots x 2^-10*|z| + pack quantum
#define MARGIN_SCALE 1.953e-3f
#define MARGIN_CONST 1.2e-3f

#define NWAVES 1024        // rescue: 256 blocks x 4 waves

using f16x8 = __attribute__((ext_vector_type(8))) _Float16;
using f32x4 = __attribute__((ext_vector_type(4))) float;

__device__ __forceinline__ f16x8 hc(uint4 v) { return __builtin_bit_cast(f16x8, v); }
__device__ __forceinline__ unsigned f16pair(float a, float b) {
    unsigned short ha = __builtin_bit_cast(unsigned short, (_Float16)a);  // RNE
    unsigned short hb = __builtin_bit_cast(unsigned short, (_Float16)b);
    return (unsigned)ha | ((unsigned)hb << 16);
}
__device__ __forceinline__ float pick4(float a0, float a1, float a2, float a3, int i) {
    float x = (i & 1) ? a1 : a0;
    float y = (i & 1) ? a3 : a2;
    return (i & 2) ? y : x;
}

// 32 blocks x 256: fp16(RNE) codebook, code-major linear; block 0 zeroes scalars.
__global__ void vq_init(const float* __restrict__ emb, float* __restrict__ ws) {
    const int tid = threadIdx.x, blk = blockIdx.x;
    if (blk == 0) {
        ws[CNT_OFF + tid] = 0.0f;
        ws[CNT_OFF + 256 + tid] = 0.0f;
        if (tid == 0) {
            ws[CDELTA_OFF] = 0.0f;
            ((int*)ws)[RC_OFF] = 0;
            ((int*)ws)[DONE_OFF] = 0;
        }
    }
    const int k  = blk * 16 + (tid >> 4);
    const int d0 = (tid & 15) * 4;
    float4 v = *reinterpret_cast<const float4*>(emb + k * DD + d0);
    uint2 w;
    w.x = f16pair(v.x, v.y);
    w.y = f16pair(v.z, v.w);
    reinterpret_cast<uint2*>(ws + EBH_OFF)[k * 16 + (d0 >> 2)] = w;
}

// Screen (unchanged from round 4): fp16 single-MFMA, 64 tokens/wave, LDS-staged,
// reg-prefetched B, 4 blocks/CU, token-adaptive rescue margin.
__global__ __launch_bounds__(256, 4) void vq_screen(
    const float* __restrict__ z_e, const float* __restrict__ emb,
    float* __restrict__ ws, float* __restrict__ out_zq, float* __restrict__ out_idx)
{
    __shared__ uint4 sh[2304];      // 256 codes * 9 uint4 (padded) = 36,864 B
    __shared__ int hist[KK];        // + 2 KB

    const int tid  = threadIdx.x;
    const int lane = tid & 63;
    const int col  = lane & 15;
    const int q    = lane >> 4;
    const int W    = (blockIdx.x << 2) | (tid >> 6);   // global wave id, 0..2047
    const int base_tok = W * 64;

    hist[tid] = 0; hist[tid + 256] = 0;

    const uint4* eb4 = reinterpret_cast<const uint4*>(ws + EBH_OFF);

    // ---- A fragments: 4 token-tiles x 2 k-frags, fp16 RNE; + per-(s) |z|^2 partials
    f16x8 af[4][2];
    float zp[4];
#pragma unroll
    for (int s = 0; s < 4; ++s) {
        zp[s] = 0.0f;
        const int n = base_tok + s * 16 + col;
        const size_t zoff = (size_t)(n >> 12) * DHT + (size_t)((n >> 8) & 15) * 256 + (size_t)(n & 255);
#pragma unroll
        for (int kf = 0; kf < 2; ++kf) {
            const int d0 = kf * 32 + q * 8;
            unsigned hu[4];
#pragma unroll
            for (int jj = 0; jj < 4; ++jj) {
                float z0 = z_e[zoff + (size_t)(d0 + 2*jj + 0) * HT];
                float z1 = z_e[zoff + (size_t)(d0 + 2*jj + 1) * HT];
                zp[s] = fmaf(z0, z0, zp[s]);
                zp[s] = fmaf(z1, z1, zp[s]);
                hu[jj] = f16pair(z0, z1);
            }
            af[s][kf] = hc(make_uint4(hu[0], hu[1], hu[2], hu[3]));
        }
    }
#pragma unroll
    for (int s = 0; s < 4; ++s) {
        zp[s] += __shfl_xor(zp[s], 16, 64);
        zp[s] += __shfl_xor(zp[s], 32, 64);
    }

    float m1[4][4], m2[4][4];
#pragma unroll
    for (int s = 0; s < 4; ++s)
#pragma unroll
        for (int r = 0; r < 4; ++r) { m1[s][r] = -3.4e38f; m2[s][r] = -3.4e38f; }

    unsigned ktag = (unsigned)col;
    const int idx0 = col * 9 + q;

#pragma unroll
    for (int p = 0; p < 2; ++p) {
        if (p) __syncthreads();
#pragma unroll
        for (int j = 0; j < 8; ++j) {
            const int local = j * 256 + tid;
            const int c = local >> 3, jj = local & 7;
            sh[c * 9 + jj] = eb4[p * 2048 + local];
        }
        __syncthreads();

        uint4 nh0 = sh[idx0], nh1 = sh[idx0 + 4];

#pragma unroll 4
        for (int ctl = 0; ctl < 16; ++ctl) {
            f16x8 b0 = hc(nh0), b1 = hc(nh1);
            if (ctl < 15) {
                const int ni = idx0 + (ctl + 1) * 144;
                nh0 = sh[ni]; nh1 = sh[ni + 4];
            }
#pragma unroll
            for (int s = 0; s < 4; ++s) {
                f32x4 acc = {0.f, 0.f, 0.f, 0.f};
                acc = __builtin_amdgcn_mfma_f32_16x16x32_f16(af[s][0], b0, acc, 0, 0, 0);
                acc = __builtin_amdgcn_mfma_f32_16x16x32_f16(af[s][1], b1, acc, 0, 0, 0);
#pragma unroll
                for (int r = 0; r < 4; ++r) {
                    float pk = __uint_as_float((__float_as_uint(acc[r]) & 0xFFFFFE00u) | ktag);
                    m2[s][r] = __builtin_amdgcn_fmed3f(pk, m1[s][r], m2[s][r]);
                    m1[s][r] = fmaxf(m1[s][r], pk);
                }
            }
            ktag += 16u;
        }
    }

#pragma unroll
    for (int msk = 1; msk <= 8; msk <<= 1) {
#pragma unroll
        for (int s = 0; s < 4; ++s)
#pragma unroll
            for (int r = 0; r < 4; ++r) {
                float o1 = __shfl_xor(m1[s][r], msk, 64);
                float o2 = __shfl_xor(m2[s][r], msk, 64);
                m2[s][r] = __builtin_amdgcn_fmed3f(m1[s][r], o1, fmaxf(m2[s][r], o2));
                m1[s][r] = fmaxf(m1[s][r], o1);
            }
    }

    const int s0 = col >> 2, r0 = col & 3;
    const int token = base_tok + s0 * 16 + q * 4 + r0;

    float m1v, m2v;
    {
        float a = pick4(m1[0][0], m1[0][1], m1[0][2], m1[0][3], r0);
        float b = pick4(m1[1][0], m1[1][1], m1[1][2], m1[1][3], r0);
        float c = pick4(m1[2][0], m1[2][1], m1[2][2], m1[2][3], r0);
        float d = pick4(m1[3][0], m1[3][1], m1[3][2], m1[3][3], r0);
        m1v = pick4(a, b, c, d, s0);
        a = pick4(m2[0][0], m2[0][1], m2[0][2], m2[0][3], r0);
        b = pick4(m2[1][0], m2[1][1], m2[1][2], m2[1][3], r0);
        c = pick4(m2[2][0], m2[2][1], m2[2][2], m2[2][3], r0);
        d = pick4(m2[3][0], m2[3][1], m2[3][2], m2[3][3], r0);
        m2v = pick4(a, b, c, d, s0);
    }
    const int c0 = q * 4 + r0;
    float z0s = __shfl(zp[0], c0, 64);
    float z1s = __shfl(zp[1], c0, 64);
    float z2s = __shfl(zp[2], c0, 64);
    float z3s = __shfl(zp[3], c0, 64);
    const float zsqv = pick4(z0s, z1s, z2s, z3s, s0);

    const int k_sel = (int)(__float_as_uint(m1v) & 511u);
    const float dminA = fmaf(-2.0f, m1v, zsqv + 1.0f);

    out_idx[token] = (float)k_sel;
    const float margin = MARGIN_SCALE * sqrtf(zsqv) + MARGIN_CONST;
    if (m1v - m2v < margin) {
        int* rc = (int*)ws + RC_OFF;
        int pp = atomicAdd(rc, 1);
        if (pp < RMAX) {
            int* rl = (int*)ws + RLIST_OFF;
            rl[2 * pp] = token;
            rl[2 * pp + 1] = (int)__float_as_uint(dminA);
        }
    }
    atomicAdd(&hist[k_sel], 1);

    float csum = dminA;
#pragma unroll
    for (int off = 32; off > 0; off >>= 1) csum += __shfl_down(csum, off, 64);
    if (lane == 0) ws[CPART_OFF + W] = csum;

    {
        const int b = token >> 12, h = (token >> 8) & 15, t = token & 255;
        const size_t zb = (size_t)b * DHT + (size_t)h * TT + (size_t)t;
        const float4* er = reinterpret_cast<const float4*>(emb + (size_t)k_sel * DD);
#pragma unroll
        for (int i = 0; i < 16; ++i) {
            float4 v = er[i];
            out_zq[zb + (size_t)(4*i+0) * HT] = v.x;
            out_zq[zb + (size_t)(4*i+1) * HT] = v.y;
            out_zq[zb + (size_t)(4*i+2) * HT] = v.z;
            out_zq[zb + (size_t)(4*i+3) * HT] = v.w;
        }
    }

    __syncthreads();
    int c = hist[tid];       if (c) atomicAdd(ws + CNT_OFF + tid,       (float)c);
    c     = hist[tid + 256]; if (c) atomicAdd(ws + CNT_OFF + tid + 256, (float)c);
}

// Rescue v5: wave-per-token-pair, ZERO barriers in the token loop, no per-thread
// arrays beyond 24 floats (spill-proof). fp32 codebook in LDS chunk-major
// ecb[j*512+k] (128 KB, staged once). Lane l owns codes {l+64c}, scores 2 tokens
// per pass (160 conflict-free b128 reads + 1024 FMA). Exact compare + lowest-index
// tie-break. One commit atomic per wave. Fused stats via last-block gate.
__global__ __launch_bounds__(256) void vq_rescue_stats(
    const float* __restrict__ z_e, const float* __restrict__ emb,
    float* __restrict__ ws, float* __restrict__ out, float* __restrict__ out_idx)
{
    __shared__ float4 ecb[8192];       // [chunk j][code k] = ecb[j*512+k], 128 KB
    __shared__ float4 zbuf[4][2][16];  // [wave][slot][chunk], 2 KB
    __shared__ float  sdV[256];
    __shared__ int    siV[256];
    __shared__ float  scom[256];
    __shared__ int    amlast;

    float* out_zq = out;
    const int tid = threadIdx.x;
    const int wv  = tid >> 6, ln = tid & 63;
    int cnt = ((const int*)ws)[RC_OFF];
    if (cnt > RMAX) cnt = RMAX;
    const int* rl = (const int*)ws + RLIST_OFF;

    // ---- stage fp32 codebook chunk-major (one pass, coalesced, conflict-free) ----
    {
        const float4* eg = reinterpret_cast<const float4*>(emb);
        for (int t = tid; t < 8192; t += 256)
            ecb[(t & 15) * 512 + (t >> 4)] = eg[t];
    }
    __syncthreads();

    // per-lane |e|^2 for my 8 codes (k = ln + 64c)
    float esq[8];
#pragma unroll
    for (int c = 0; c < 8; ++c) {
        float s = 0.f;
#pragma unroll
        for (int j = 0; j < 16; ++j) {
            float4 e = ecb[j * 512 + ln + 64 * c];
            s = fmaf(e.x, e.x, s); s = fmaf(e.y, e.y, s);
            s = fmaf(e.z, e.z, s); s = fmaf(e.w, e.w, s);
        }
        esq[c] = s;
    }

    const int gw = (blockIdx.x << 2) | wv;    // global wave 0..1023
    float* zslot0 = reinterpret_cast<float*>(&zbuf[wv][0][0]);
    float* zslot1 = reinterpret_cast<float*>(&zbuf[wv][1][0]);
    float cdacc = 0.0f;

    for (int it = gw * 2; it < cnt; it += 2 * NWAVES) {
        const int  i1ok = (it + 1 < cnt);
        const int  n0 = rl[2 * it];
        const float dm0 = __uint_as_float((unsigned)rl[2 * it + 1]);
        const int  n1 = i1ok ? rl[2 * it + 2] : n0;
        const float dm1 = i1ok ? __uint_as_float((unsigned)rl[2 * it + 3]) : dm0;
        const size_t zo0 = (size_t)(n0 >> 12) * DHT + (size_t)((n0 >> 8) & 15) * 256 + (size_t)(n0 & 255);
        const size_t zo1 = (size_t)(n1 >> 12) * DHT + (size_t)((n1 >> 8) & 15) * 256 + (size_t)(n1 & 255);

        // gather z for both tokens (lane = dimension); stash to wave-private LDS
        const float z0 = z_e[zo0 + (size_t)ln * HT];
        const float z1 = z_e[zo1 + (size_t)ln * HT];
        zslot0[ln] = z0;
        zslot1[ln] = z1;

        // |z|^2 via butterfly (all lanes get it)
        float s0 = z0 * z0, s1 = z1 * z1;
#pragma unroll
        for (int off = 1; off < 64; off <<= 1) {
            s0 += __shfl_xor(s0, off, 64);
            s1 += __shfl_xor(s1, off, 64);
        }

        // dots: 8 codes x 2 tokens
        float a0[8], a1[8];
#pragma unroll
        for (int c = 0; c < 8; ++c) { a0[c] = 0.f; a1[c] = 0.f; }
#pragma unroll
        for (int j = 0; j < 16; ++j) {
            const float4 za = zbuf[wv][0][j];
            const float4 zb = zbuf[wv][1][j];
#pragma unroll
            for (int c = 0; c < 8; ++c) {
                const float4 e = ecb[j * 512 + ln + 64 * c];
                a0[c] = fmaf(e.x, za.x, a0[c]); a0[c] = fmaf(e.y, za.y, a0[c]);
                a0[c] = fmaf(e.z, za.z, a0[c]); a0[c] = fmaf(e.w, za.w, a0[c]);
                a1[c] = fmaf(e.x, zb.x, a1[c]); a1[c] = fmaf(e.y, zb.y, a1[c]);
                a1[c] = fmaf(e.z, zb.z, a1[c]); a1[c] = fmaf(e.w, zb.w, a1[c]);
            }
        }

        // winner per token: v = esq - 2*dot (zsq added later); exact lowest-k ties
        float v0 = fmaf(-2.f, a0[0], esq[0]); int k0 = ln;
        float v1 = fmaf(-2.f, a1[0], esq[0]); int k1 = ln;
#pragma unroll
        for (int c = 1; c < 8; ++c) {
            const int kc = ln + 64 * c;
            float t0 = fmaf(-2.f, a0[c], esq[c]);
            float t1 = fmaf(-2.f, a1[c], esq[c]);
            if (t0 < v0) { v0 = t0; k0 = kc; }
            if (t1 < v1) { v1 = t1; k1 = kc; }
        }
#pragma unroll
        for (int off = 1; off < 64; off <<= 1) {
            float ov0 = __shfl_xor(v0, off, 64); int ok0 = __shfl_xor(k0, off, 64);
            float ov1 = __shfl_xor(v1, off, 64); int ok1 = __shfl_xor(k1, off, 64);
            if (ov0 < v0 || (ov0 == v0 && ok0 < k0)) { v0 = ov0; k0 = ok0; }
            if (ov1 < v1 || (ov1 == v1 && ok1 < k1)) { v1 = ov1; k1 = ok1; }
        }

        // ---- token 0 finalize (wave-uniform) ----
        {
            const int kold = (int)out_idx[n0];
            if (ln == 0) {
                cdacc += (s0 + v0) - dm0;
                if (k0 != kold) {
                    out_idx[n0] = (float)k0;
                    atomicAdd(ws + CNT_OFF + kold, -1.0f);
                    atomicAdd(ws + CNT_OFF + k0,    1.0f);
                }
            }
            if (k0 != kold) {   // patch z_q: lane = dimension
                const float4 e4 = ecb[(ln >> 2) * 512 + k0];
                out_zq[zo0 + (size_t)ln * HT] = pick4(e4.x, e4.y, e4.z, e4.w, ln & 3);
            }
        }
        // ---- token 1 finalize ----
        if (i1ok) {
            const int kold = (int)out_idx[n1];
            if (ln == 0) {
                cdacc += (s1 + v1) - dm1;
                if (k1 != kold) {
                    out_idx[n1] = (float)k1;
                    atomicAdd(ws + CNT_OFF + kold, -1.0f);
                    atomicAdd(ws + CNT_OFF + k1,    1.0f);
                }
            }
            if (k1 != kold) {
                const float4 e4 = ecb[(ln >> 2) * 512 + k1];
                out_zq[zo1 + (size_t)ln * HT] = pick4(e4.x, e4.y, e4.z, e4.w, ln & 3);
            }
        }
    }

    if (ln == 0 && cdacc != 0.0f) atomicAdd(ws + CDELTA_OFF, cdacc);

    // ---- gate: last block to finish runs the stats reduction ----
    __syncthreads();
    __threadfence();
    if (tid == 0) {
        int d = atomicAdd((int*)ws + DONE_OFF, 1);
        amlast = (d == (int)gridDim.x - 1) ? 1 : 0;
    }
    __syncthreads();
    if (!amlast) return;

    // stats: 256 threads x 2 codes each; counts/cdelta via agent-scope atomic loads
    {
        const int k = tid;
        const float c0 = __hip_atomic_load(ws + CNT_OFF + k,       __ATOMIC_RELAXED, __HIP_MEMORY_SCOPE_AGENT);
        const float c1 = __hip_atomic_load(ws + CNT_OFF + k + 256, __ATOMIC_RELAXED, __HIP_MEMORY_SCOPE_AGENT);
        const float p0 = c0 * (1.0f / (float)NN);
        const float p1 = c1 * (1.0f / (float)NN);
        sdV[k] = p0 * logf(p0 + 1e-12f) + p1 * logf(p1 + 1e-12f);
        siV[k] = ((p0 > 0.0f) ? 1 : 0) + ((p1 > 0.0f) ? 1 : 0);
        float cs = 0.0f;
#pragma unroll
        for (int i = 0; i < 8; ++i) cs += ws[CPART_OFF + k + 256 * i];
        scom[k] = cs;
        __syncthreads();
        for (int off = 128; off > 0; off >>= 1) {
            if (k < off) {
                sdV[k]  += sdV[k + off];
                siV[k]  += siV[k + off];
                scom[k] += scom[k + off];
            }
            __syncthreads();
        }
        if (k == 0) {
            float cdelta = __hip_atomic_load(ws + CDELTA_OFF, __ATOMIC_RELAXED, __HIP_MEMORY_SCOPE_AGENT);
            out[COMMIT_OFF] = 0.25f * (scom[0] + cdelta) / (float)ZQ_SIZE;
            out[PPL_OFF]    = expf(-sdV[0]);
            out[USE_OFF]    = (float)siV[0] / (float)KK;
        }
    }
}

extern "C" void kernel_launch(void* const* d_in, const int* in_sizes, int n_in,
                              void* d_out, int out_size, void* d_ws, size_t ws_size,
                              hipStream_t stream) {
    const float* z_e = (const float*)d_in[0];
    const float* emb = (const float*)d_in[1];
    float* out = (float*)d_out;
    float* ws  = (float*)d_ws;

    float* out_idx = out + IDX_OFF;

    vq_init<<<32, 256, 0, stream>>>(emb, ws);
    vq_screen<<<512, 256, 0, stream>>>(z_e, emb, ws, out, out_idx);
    vq_rescue_stats<<<256, 256, 0, stream>>>(z_e, emb, ws, out, out_idx);
}